// Round 13
// baseline (158.558 us; speedup 1.0000x reference)
//
#include <hip/hip_runtime.h>
#include <hip/hip_fp16.h>

#define D 96
#define D4 24
#define MAXBINS 256   // buckets of 256 nodes; n <= 65536

static inline size_t alignup(size_t x) { return (x + 255) & ~size_t(255); }

__device__ inline float4 f4fma(float s, float4 a, float4 acc) {
    acc.x = fmaf(s, a.x, acc.x);
    acc.y = fmaf(s, a.y, acc.y);
    acc.z = fmaf(s, a.z, acc.z);
    acc.w = fmaf(s, a.w, acc.w);
    return acc;
}

// unpack 8 fp16 (uint4) and ADD into two float4 accumulators
__device__ inline void u4add(uint4 rv, float4& a0, float4& a1) {
    __half2 h0 = *reinterpret_cast<__half2*>(&rv.x);
    __half2 h1 = *reinterpret_cast<__half2*>(&rv.y);
    __half2 h2 = *reinterpret_cast<__half2*>(&rv.z);
    __half2 h3 = *reinterpret_cast<__half2*>(&rv.w);
    float2 f0 = __half22float2(h0);
    float2 f1 = __half22float2(h1);
    float2 f2 = __half22float2(h2);
    float2 f3 = __half22float2(h3);
    a0.x += f0.x; a0.y += f0.y; a0.z += f1.x; a0.w += f1.y;
    a1.x += f2.x; a1.y += f2.y; a1.z += f3.x; a1.w += f3.y;
}

__device__ inline uint4 pack8(float4 v0, float4 v1) {
    __half2 h0 = __float22half2_rn(make_float2(v0.x, v0.y));
    __half2 h1 = __float22half2_rn(make_float2(v0.z, v0.w));
    __half2 h2 = __float22half2_rn(make_float2(v1.x, v1.y));
    __half2 h3 = __float22half2_rn(make_float2(v1.z, v1.w));
    uint4 r;
    r.x = *reinterpret_cast<unsigned int*>(&h0);
    r.y = *reinterpret_cast<unsigned int*>(&h1);
    r.z = *reinterpret_cast<unsigned int*>(&h2);
    r.w = *reinterpret_cast<unsigned int*>(&h3);
    return r;
}

__device__ inline void unpack8(uint4 rv, float* f) {
    __half2 h0 = *reinterpret_cast<__half2*>(&rv.x);
    __half2 h1 = *reinterpret_cast<__half2*>(&rv.y);
    __half2 h2 = *reinterpret_cast<__half2*>(&rv.z);
    __half2 h3 = *reinterpret_cast<__half2*>(&rv.w);
    float2 f0 = __half22float2(h0);
    float2 f1 = __half22float2(h1);
    float2 f2 = __half22float2(h2);
    float2 f3 = __half22float2(h3);
    f[0] = f0.x; f[1] = f0.y; f[2] = f1.x; f[3] = f1.y;
    f[4] = f2.x; f[5] = f2.y; f[6] = f3.x; f[7] = f3.y;
}

// ---- bucket-sort pipeline (no per-edge global atomics) ----

__global__ __launch_bounds__(1024) void hist_kernel(const int* __restrict__ dst, int E,
                                                    int* __restrict__ bhist, int nbins) {
    __shared__ int h[MAXBINS];
    const int tid = threadIdx.x;
    if (tid < nbins) h[tid] = 0;
    __syncthreads();
    int e = blockIdx.x * 1024 + tid;
    if (e < E) atomicAdd(&h[dst[e] >> 8], 1);
    __syncthreads();
    if (tid < nbins) bhist[blockIdx.x * nbins + tid] = h[tid];
}

__global__ __launch_bounds__(1024) void scan1_kernel(const int* __restrict__ bhist,
                                                     int* __restrict__ boffs,
                                                     int* __restrict__ bsum,
                                                     int m, int nblk, int nbins) {
    __shared__ int wsum[16];
    const int i = blockIdx.x * 1024 + threadIdx.x;
    const int lane = threadIdx.x & 63;
    const int wid  = threadIdx.x >> 6;
    int v = 0;
    if (i < m) {
        int b = i % nblk, bin = i / nblk;
        v = bhist[b * nbins + bin];
    }
    int sc = v;
    #pragma unroll
    for (int off = 1; off < 64; off <<= 1) {
        int t = __shfl_up(sc, off);
        if (lane >= off) sc += t;
    }
    if (lane == 63) wsum[wid] = sc;
    __syncthreads();
    int wprefix = 0;
    #pragma unroll
    for (int k = 0; k < 16; ++k)
        if (k < wid) wprefix += wsum[k];
    if (i < m) boffs[i] = wprefix + (sc - v);
    if (threadIdx.x == 1023) bsum[blockIdx.x] = wprefix + sc;
}

__global__ __launch_bounds__(1024) void scan2_kernel(const int* __restrict__ bsum,
                                                     int* __restrict__ boff, int nb) {
    __shared__ int wsum[16];
    const int lane = threadIdx.x & 63;
    const int wid  = threadIdx.x >> 6;
    int v = ((int)threadIdx.x < nb) ? bsum[threadIdx.x] : 0;
    int sc = v;
    #pragma unroll
    for (int off = 1; off < 64; off <<= 1) {
        int t = __shfl_up(sc, off);
        if (lane >= off) sc += t;
    }
    if (lane == 63) wsum[wid] = sc;
    __syncthreads();
    int wprefix = 0;
    #pragma unroll
    for (int k = 0; k < 16; ++k)
        if (k < wid) wprefix += wsum[k];
    if ((int)threadIdx.x < nb) boff[threadIdx.x] = wprefix + (sc - v);
}

__global__ __launch_bounds__(1024) void dist_kernel(const int* __restrict__ src,
                                                    const int* __restrict__ dst, int E,
                                                    const int* __restrict__ boffs,
                                                    const int* __restrict__ bboff,
                                                    int nblk, int nbins,
                                                    int* __restrict__ esrc,
                                                    unsigned char* __restrict__ ed8) {
    __shared__ int h[MAXBINS];
    __shared__ int base[MAXBINS];
    const int tid = threadIdx.x;
    if (tid < nbins) h[tid] = 0;
    __syncthreads();
    int e = blockIdx.x * 1024 + tid;
    int s = 0, d = 0, bin = 0, rank = 0;
    bool valid = e < E;
    if (valid) {
        s = src[e]; d = dst[e];
        bin = d >> 8;
        rank = atomicAdd(&h[bin], 1);
    }
    __syncthreads();
    if (tid < nbins) {
        int idx = tid * nblk + blockIdx.x;
        base[tid] = boffs[idx] + bboff[idx >> 10];
    }
    __syncthreads();
    if (valid) {
        int pos = base[bin] + rank;
        esrc[pos] = s;
        ed8[pos] = (unsigned char)(d & 255);
    }
}

// One workgroup per bucket (256 nodes). Pass 1: degrees + prefix -> dinv,rowptr.
// Bucket-local counting sort by degree -> perm (perm[j] stays within j's bucket,
// so aggregate output writes stay in a 96KB window). Pass 2: rank edges, write
// src-only CSR (contiguous per bucket). No cross-workgroup reads: legal fuse.
__global__ __launch_bounds__(256) void bucketAB_kernel(const int* __restrict__ esrc,
                                                       const unsigned char* __restrict__ ed8,
                                                       const int* __restrict__ boffs,
                                                       const int* __restrict__ bboff,
                                                       int nblk, int nbins,
                                                       float* __restrict__ dinv,
                                                       int* __restrict__ rowptr,
                                                       int* __restrict__ csr,
                                                       int* __restrict__ perm,
                                                       int n, int E) {
    __shared__ int cnt[256];
    __shared__ int cur[256];
    __shared__ int wsum[4];
    __shared__ int dh[64];
    __shared__ int dbase[64];
    const int k = blockIdx.x;
    const int tid = threadIdx.x;
    int i0 = k * nblk, i1 = (k + 1) * nblk;
    const int bstart = boffs[i0] + bboff[i0 >> 10];
    const int bend = (k + 1 < nbins) ? (boffs[i1] + bboff[i1 >> 10]) : E;
    cnt[tid] = 0;
    if (tid < 64) dh[tid] = 0;
    __syncthreads();
    for (int e = bstart + tid; e < bend; e += 256)
        atomicAdd(&cnt[ed8[e]], 1);
    __syncthreads();
    int v = cnt[tid];
    const int lane = tid & 63, wid = tid >> 6;
    int sc = v;
    #pragma unroll
    for (int off = 1; off < 64; off <<= 1) {
        int t = __shfl_up(sc, off);
        if (lane >= off) sc += t;
    }
    if (lane == 63) wsum[wid] = sc;
    int node = k * 256 + tid;
    int dbin = v < 63 ? v : 63;
    if (node < n) atomicAdd(&dh[dbin], 1);
    __syncthreads();
    int wprefix = 0;
    #pragma unroll
    for (int w = 0; w < 4; ++w)
        if (w < wid) wprefix += wsum[w];
    int mybase = bstart + wprefix + (sc - v);
    if (node < n) {
        dinv[node] = rsqrtf((float)(v + 1));      // +1 = self-loop
        rowptr[node] = mybase;
    }
    if (k == nbins - 1 && tid == 0) rowptr[n] = E;
    cur[tid] = mybase;
    // exclusive scan of the 64-bin degree histogram (wave 0)
    if (tid < 64) {
        int vv = dh[tid];
        int s2 = vv;
        #pragma unroll
        for (int off = 1; off < 64; off <<= 1) {
            int t2 = __shfl_up(s2, off);
            if (tid >= off) s2 += t2;
        }
        dbase[tid] = s2 - vv;
    }
    __syncthreads();
    if (node < n) {
        int pos = atomicAdd(&dbase[dbin], 1);
        perm[k * 256 + pos] = node;     // bucket-local: pos < valid count
    }
    for (int e = bstart + tid; e < bend; e += 256) {
        int pos = atomicAdd(&cur[ed8[e]], 1);
        csr[pos] = esrc[e];
    }
}

// ---- dense transform + aggregation ----

// Y[n,96](fp16, pre-scaled by dinv[row]) = X @ W.  X fp32 (IN16=0) or fp16 (IN16=1).
template<int IN16>
__global__ __launch_bounds__(192) void matmul_kernel(const void* __restrict__ Xv,
                                                     const float* __restrict__ W,
                                                     const float* __restrict__ dinv,
                                                     uint2* __restrict__ Y, int n) {
    __shared__ float XsT[96 * 64];
    const int t = threadIdx.x;        // 0..23 col-group
    const int y = threadIdx.y;        // 0..7 row-group
    const int tid = y * 24 + t;
    const int row0 = blockIdx.x * 64;

    if (IN16) {
        const uint4* XH = (const uint4*)Xv;
        for (int i = tid; i < 64 * 12; i += 192) {
            int r = i / 12, c8 = i % 12;
            uint4 v = make_uint4(0u, 0u, 0u, 0u);
            if (row0 + r < n) v = XH[(size_t)(row0 + r) * 12 + c8];
            float f[8];
            unpack8(v, f);
            int c4a = 2 * c8, c4b = 2 * c8 + 1;
            int rsa = r ^ ((c4a & 15) << 2);
            int rsb = r ^ ((c4b & 15) << 2);
            XsT[(c4a * 4 + 0) * 64 + rsa] = f[0];
            XsT[(c4a * 4 + 1) * 64 + rsa] = f[1];
            XsT[(c4a * 4 + 2) * 64 + rsa] = f[2];
            XsT[(c4a * 4 + 3) * 64 + rsa] = f[3];
            XsT[(c4b * 4 + 0) * 64 + rsb] = f[4];
            XsT[(c4b * 4 + 1) * 64 + rsb] = f[5];
            XsT[(c4b * 4 + 2) * 64 + rsb] = f[6];
            XsT[(c4b * 4 + 3) * 64 + rsb] = f[7];
        }
    } else {
        const float4* X4 = (const float4*)Xv;
        for (int i = tid; i < 64 * 24; i += 192) {
            int r = i / 24, c4 = i % 24;
            float4 v = make_float4(0.f, 0.f, 0.f, 0.f);
            if (row0 + r < n) v = X4[(size_t)(row0 + r) * D4 + c4];
            int rs = r ^ ((c4 & 15) << 2);
            XsT[(c4 * 4 + 0) * 64 + rs] = v.x;
            XsT[(c4 * 4 + 1) * 64 + rs] = v.y;
            XsT[(c4 * 4 + 2) * 64 + rs] = v.z;
            XsT[(c4 * 4 + 3) * 64 + rs] = v.w;
        }
    }
    __syncthreads();

    const float4* W4 = (const float4*)W;
    float4 acc[8];
    #pragma unroll
    for (int r = 0; r < 8; ++r) acc[r] = make_float4(0.f, 0.f, 0.f, 0.f);
    const int rbase = y * 8;

    #pragma unroll 8
    for (int k = 0; k < 96; ++k) {
        float4 w = W4[k * D4 + t];
        int base0 = (rbase ^ (((k >> 2) & 15) << 2));
        float4 xa = *(const float4*)&XsT[k * 64 + base0];
        float4 xb = *(const float4*)&XsT[k * 64 + (base0 ^ 4)];
        acc[0] = f4fma(xa.x, w, acc[0]);
        acc[1] = f4fma(xa.y, w, acc[1]);
        acc[2] = f4fma(xa.z, w, acc[2]);
        acc[3] = f4fma(xa.w, w, acc[3]);
        acc[4] = f4fma(xb.x, w, acc[4]);
        acc[5] = f4fma(xb.y, w, acc[5]);
        acc[6] = f4fma(xb.z, w, acc[6]);
        acc[7] = f4fma(xb.w, w, acc[7]);
    }

    #pragma unroll
    for (int r = 0; r < 8; ++r) {
        int row = row0 + rbase + r;
        if (row < n) {
            float sc = dinv[row];
            __half2 ha = __float22half2_rn(make_float2(sc * acc[r].x, sc * acc[r].y));
            __half2 hb = __float22half2_rn(make_float2(sc * acc[r].z, sc * acc[r].w));
            uint2 st;
            st.x = *reinterpret_cast<unsigned int*>(&ha);
            st.y = *reinterpret_cast<unsigned int*>(&hb);
            Y[(size_t)row * D4 + t] = st;
        }
    }
}

// out[i,:] = prelu( dinv[i]*( sum_e XWS[src_e,:] + XWS[i,:] ) + b ), XWS fp16 pre-scaled.
// block (12,32); nodes via bucket-local degree-sorted perm (uniform wave trip counts,
// output writes stay within the node's 256-row bucket window).
// OUT16=1 -> fp16 rows (layer-1 h); OUT16=0 -> fp32 rows (final d_out).
template<int OUT16>
__global__ __launch_bounds__(384) void aggregate_kernel(const uint4* __restrict__ XH4,
                                                        const int* __restrict__ csr,
                                                        const int* __restrict__ rowptr,
                                                        const float* __restrict__ dinv,
                                                        const int* __restrict__ perm,
                                                        const float4* __restrict__ b4,
                                                        const float4* __restrict__ pa4,
                                                        void* __restrict__ outv, int n) {
    const int j = blockIdx.x * 32 + threadIdx.y;
    const int t = threadIdx.x;  // 0..11
    if (j >= n) return;
    const int i = perm[j];
    const int beg = rowptr[i], end = rowptr[i + 1];
    float4 a0 = make_float4(0.f, 0.f, 0.f, 0.f);
    float4 a1 = make_float4(0.f, 0.f, 0.f, 0.f);
    int p = beg;
    for (; p + 8 <= end; p += 8) {
        int s0 = csr[p + 0];
        int s1 = csr[p + 1];
        int s2 = csr[p + 2];
        int s3 = csr[p + 3];
        int s4 = csr[p + 4];
        int s5 = csr[p + 5];
        int s6 = csr[p + 6];
        int s7 = csr[p + 7];
        uint4 r0 = XH4[(size_t)s0 * 12 + t];
        uint4 r1 = XH4[(size_t)s1 * 12 + t];
        uint4 r2 = XH4[(size_t)s2 * 12 + t];
        uint4 r3 = XH4[(size_t)s3 * 12 + t];
        uint4 r4 = XH4[(size_t)s4 * 12 + t];
        uint4 r5 = XH4[(size_t)s5 * 12 + t];
        uint4 r6 = XH4[(size_t)s6 * 12 + t];
        uint4 r7 = XH4[(size_t)s7 * 12 + t];
        u4add(r0, a0, a1);
        u4add(r1, a0, a1);
        u4add(r2, a0, a1);
        u4add(r3, a0, a1);
        u4add(r4, a0, a1);
        u4add(r5, a0, a1);
        u4add(r6, a0, a1);
        u4add(r7, a0, a1);
    }
    if (p + 4 <= end) {
        int s0 = csr[p + 0];
        int s1 = csr[p + 1];
        int s2 = csr[p + 2];
        int s3 = csr[p + 3];
        uint4 r0 = XH4[(size_t)s0 * 12 + t];
        uint4 r1 = XH4[(size_t)s1 * 12 + t];
        uint4 r2 = XH4[(size_t)s2 * 12 + t];
        uint4 r3 = XH4[(size_t)s3 * 12 + t];
        u4add(r0, a0, a1);
        u4add(r1, a0, a1);
        u4add(r2, a0, a1);
        u4add(r3, a0, a1);
        p += 4;
    }
    for (; p < end; ++p)
        u4add(XH4[(size_t)csr[p] * 12 + t], a0, a1);
    // self term (pre-scaled row)
    u4add(XH4[(size_t)i * 12 + t], a0, a1);
    const float di = dinv[i];
    float4 b0 = b4[2 * t], b1 = b4[2 * t + 1];
    float4 q0 = pa4[2 * t], q1 = pa4[2 * t + 1];
    float4 v0, v1;
    v0.x = fmaf(di, a0.x, b0.x);
    v0.y = fmaf(di, a0.y, b0.y);
    v0.z = fmaf(di, a0.z, b0.z);
    v0.w = fmaf(di, a0.w, b0.w);
    v1.x = fmaf(di, a1.x, b1.x);
    v1.y = fmaf(di, a1.y, b1.y);
    v1.z = fmaf(di, a1.z, b1.z);
    v1.w = fmaf(di, a1.w, b1.w);
    v0.x = v0.x > 0.f ? v0.x : q0.x * v0.x;
    v0.y = v0.y > 0.f ? v0.y : q0.y * v0.y;
    v0.z = v0.z > 0.f ? v0.z : q0.z * v0.z;
    v0.w = v0.w > 0.f ? v0.w : q0.w * v0.w;
    v1.x = v1.x > 0.f ? v1.x : q1.x * v1.x;
    v1.y = v1.y > 0.f ? v1.y : q1.y * v1.y;
    v1.z = v1.z > 0.f ? v1.z : q1.z * v1.z;
    v1.w = v1.w > 0.f ? v1.w : q1.w * v1.w;
    if (OUT16) {
        ((uint4*)outv)[(size_t)i * 12 + t] = pack8(v0, v1);
    } else {
        float4* out4 = (float4*)outv;
        out4[(size_t)i * D4 + 2 * t] = v0;
        out4[(size_t)i * D4 + 2 * t + 1] = v1;
    }
}

extern "C" void kernel_launch(void* const* d_in, const int* in_sizes, int n_in,
                              void* d_out, int out_size, void* d_ws, size_t ws_size,
                              hipStream_t stream) {
    const float* x   = (const float*)d_in[0];
    const int*   ei  = (const int*)d_in[1];
    const float* W1  = (const float*)d_in[2];
    const float* b1  = (const float*)d_in[3];
    const float* W2  = (const float*)d_in[4];
    const float* b2  = (const float*)d_in[5];
    const float* pa  = (const float*)d_in[6];
    const int n = in_sizes[0] / D;
    const int E = in_sizes[1] / 2;
    const int* srcp = ei;
    const int* dstp = ei + E;

    const int nbins  = (n + 255) / 256;
    const int nblk_e = (E + 1023) / 1024;
    const int m      = nbins * nblk_e;
    const int nbscan = (m + 1023) / 1024;

    char* w = (char*)d_ws;
    int*   bhist  = (int*)w;   w += alignup((size_t)m * 4);
    int*   boffs  = (int*)w;   w += alignup((size_t)m * 4);
    int*   bsum   = (int*)w;   w += alignup(1024 * 4);
    int*   bboff  = (int*)w;   w += alignup(1024 * 4);
    float* dinv   = (float*)w; w += alignup((size_t)n * 4);
    int*   rowptr = (int*)w;   w += alignup((size_t)(n + 1) * 4);
    int*   perm   = (int*)w;   w += alignup((size_t)n * 4);
    int*   esrc   = (int*)w;   w += alignup((size_t)E * 4);
    unsigned char* ed8 = (unsigned char*)w;  w += alignup((size_t)E);
    int*   csr    = (int*)w;   w += alignup((size_t)E * 4);
    uint4* xw     = (uint4*)w; w += alignup((size_t)n * D * 2);  // fp16 pre-scaled rows
    uint4* h16    = (uint4*)w; w += alignup((size_t)n * D * 2);  // fp16 layer-1 output
    float* out    = (float*)d_out;

    hist_kernel<<<nblk_e, 1024, 0, stream>>>(dstp, E, bhist, nbins);
    scan1_kernel<<<nbscan, 1024, 0, stream>>>(bhist, boffs, bsum, m, nblk_e, nbins);
    scan2_kernel<<<1, 1024, 0, stream>>>(bsum, bboff, nbscan);
    dist_kernel<<<nblk_e, 1024, 0, stream>>>(srcp, dstp, E, boffs, bboff, nblk_e, nbins,
                                             esrc, ed8);
    bucketAB_kernel<<<nbins, 256, 0, stream>>>(esrc, ed8, boffs, bboff, nblk_e, nbins,
                                               dinv, rowptr, csr, perm, n, E);

    dim3 mblk(24, 8);
    const int mgrid = (n + 63) / 64;
    dim3 ablk(12, 32);
    const int agrid = (n + 31) / 32;

    matmul_kernel<0><<<mgrid, mblk, 0, stream>>>(x, W1, dinv, (uint2*)xw, n);
    aggregate_kernel<1><<<agrid, ablk, 0, stream>>>(xw, csr, rowptr, dinv, perm,
                                                    (const float4*)b1, (const float4*)pa, h16, n);
    matmul_kernel<1><<<mgrid, mblk, 0, stream>>>(h16, W2, dinv, (uint2*)xw, n);
    aggregate_kernel<0><<<agrid, ablk, 0, stream>>>(xw, csr, rowptr, dinv, perm,
                                                    (const float4*)b2, (const float4*)pa, out, n);
}

// Round 14
// 136.177 us; speedup vs baseline: 1.1644x; 1.1644x over previous
//
#include <hip/hip_runtime.h>
#include <hip/hip_fp16.h>

#define D 96
#define D4 24
#define MAXBINS 256
#define CAP 16384   // slab capacity per 256-node bucket (avg fill ~4096)

static inline size_t alignup(size_t x) { return (x + 255) & ~size_t(255); }

__device__ inline float4 f4fma(float s, float4 a, float4 acc) {
    acc.x = fmaf(s, a.x, acc.x);
    acc.y = fmaf(s, a.y, acc.y);
    acc.z = fmaf(s, a.z, acc.z);
    acc.w = fmaf(s, a.w, acc.w);
    return acc;
}

// unpack 4 fp16 (uint2) and ADD into a float4 accumulator
__device__ inline void u2add(uint2 rv, float4& a) {
    __half2 h0 = *reinterpret_cast<__half2*>(&rv.x);
    __half2 h1 = *reinterpret_cast<__half2*>(&rv.y);
    float2 f0 = __half22float2(h0);
    float2 f1 = __half22float2(h1);
    a.x += f0.x; a.y += f0.y; a.z += f1.x; a.w += f1.y;
}

// cursor[b] = b*CAP  (slab base per bucket)
__global__ __launch_bounds__(256) void init_kernel(int* __restrict__ cursor) {
    cursor[threadIdx.x] = (int)threadIdx.x * CAP;
}

// 196 blocks x 4096 edges: LDS histogram -> one global ticket per (block,bucket)
// -> ranked write of packed (d8<<16|src) into the bucket slab. No scans needed.
__global__ __launch_bounds__(1024) void dist_kernel(const int* __restrict__ src,
                                                    const int* __restrict__ dst, int E,
                                                    int* __restrict__ cursor,
                                                    int* __restrict__ ebuf) {
    __shared__ int h[MAXBINS];
    __shared__ int base[MAXBINS];
    const int tid = threadIdx.x;
    if (tid < MAXBINS) h[tid] = 0;
    __syncthreads();
    const int e0 = blockIdx.x * 4096 + tid;
    int pk[4], bn[4], rk[4];
    bool val[4];
    #pragma unroll
    for (int q = 0; q < 4; ++q) {
        int e = e0 + q * 1024;
        val[q] = e < E;
        if (val[q]) {
            int s = src[e], d = dst[e];
            bn[q] = d >> 8;
            pk[q] = ((d & 255) << 16) | s;      // src < 65536
            rk[q] = atomicAdd(&h[bn[q]], 1);
        }
    }
    __syncthreads();
    if (tid < MAXBINS && h[tid]) base[tid] = atomicAdd(&cursor[tid], h[tid]);
    __syncthreads();
    #pragma unroll
    for (int q = 0; q < 4; ++q)
        if (val[q]) ebuf[base[bn[q]] + rk[q]] = pk[q];
}

// One workgroup per bucket. Pass 1: per-node counts + prefix -> dinv, rowspan
// (slab-indexed!). Pass 2: rank edges, write src-only CSR into the slab region.
// No cross-workgroup reads -> single launch is legal.
__global__ __launch_bounds__(256) void bucketAB_kernel(const int* __restrict__ ebuf,
                                                       const int* __restrict__ cursor,
                                                       float* __restrict__ dinv,
                                                       int2* __restrict__ rowspan,
                                                       int* __restrict__ csr, int n) {
    __shared__ int cnt[256];
    __shared__ int cur[256];
    __shared__ int wsum[4];
    const int k = blockIdx.x;
    const int tid = threadIdx.x;
    const int bstart = k * CAP;
    const int bend = cursor[k];          // slab fill level after dist
    cnt[tid] = 0;
    __syncthreads();
    for (int e = bstart + tid; e < bend; e += 256)
        atomicAdd(&cnt[(ebuf[e] >> 16) & 255], 1);
    __syncthreads();
    int v = cnt[tid];
    const int lane = tid & 63, wid = tid >> 6;
    int sc = v;
    #pragma unroll
    for (int off = 1; off < 64; off <<= 1) {
        int t = __shfl_up(sc, off);
        if (lane >= off) sc += t;
    }
    if (lane == 63) wsum[wid] = sc;
    __syncthreads();
    int wprefix = 0;
    #pragma unroll
    for (int w = 0; w < 4; ++w)
        if (w < wid) wprefix += wsum[w];
    int mybase = bstart + wprefix + (sc - v);
    int node = k * 256 + tid;
    if (node < n) {
        dinv[node] = rsqrtf((float)(v + 1));       // +1 = self-loop
        rowspan[node] = make_int2(mybase, mybase + v);
    }
    cur[tid] = mybase;
    __syncthreads();
    for (int e = bstart + tid; e < bend; e += 256) {
        int pe = ebuf[e];
        int pos = atomicAdd(&cur[(pe >> 16) & 255], 1);
        csr[pos] = pe & 0xFFFF;
    }
}

// ---- dense transform + aggregation ----

// Y[n,96](fp16, pre-scaled by dinv[row]) = X[n,96](fp32) @ W[96,96](fp32).
__global__ __launch_bounds__(192) void matmul_kernel(const float* __restrict__ X,
                                                     const float* __restrict__ W,
                                                     const float* __restrict__ dinv,
                                                     uint2* __restrict__ Y, int n) {
    __shared__ float XsT[96 * 64];
    const int t = threadIdx.x;        // 0..23 col-group
    const int y = threadIdx.y;        // 0..7 row-group
    const int tid = y * 24 + t;
    const int row0 = blockIdx.x * 64;
    const float4* X4 = (const float4*)X;

    for (int i = tid; i < 64 * 24; i += 192) {
        int r = i / 24, c4 = i % 24;
        float4 v = make_float4(0.f, 0.f, 0.f, 0.f);
        if (row0 + r < n) v = X4[(size_t)(row0 + r) * D4 + c4];
        int rs = r ^ ((c4 & 15) << 2);
        XsT[(c4 * 4 + 0) * 64 + rs] = v.x;
        XsT[(c4 * 4 + 1) * 64 + rs] = v.y;
        XsT[(c4 * 4 + 2) * 64 + rs] = v.z;
        XsT[(c4 * 4 + 3) * 64 + rs] = v.w;
    }
    __syncthreads();

    const float4* W4 = (const float4*)W;
    float4 acc[8];
    #pragma unroll
    for (int r = 0; r < 8; ++r) acc[r] = make_float4(0.f, 0.f, 0.f, 0.f);
    const int rbase = y * 8;

    #pragma unroll 8
    for (int k = 0; k < 96; ++k) {
        float4 w = W4[k * D4 + t];
        int base0 = (rbase ^ (((k >> 2) & 15) << 2));
        float4 xa = *(const float4*)&XsT[k * 64 + base0];
        float4 xb = *(const float4*)&XsT[k * 64 + (base0 ^ 4)];
        acc[0] = f4fma(xa.x, w, acc[0]);
        acc[1] = f4fma(xa.y, w, acc[1]);
        acc[2] = f4fma(xa.z, w, acc[2]);
        acc[3] = f4fma(xa.w, w, acc[3]);
        acc[4] = f4fma(xb.x, w, acc[4]);
        acc[5] = f4fma(xb.y, w, acc[5]);
        acc[6] = f4fma(xb.z, w, acc[6]);
        acc[7] = f4fma(xb.w, w, acc[7]);
    }

    #pragma unroll
    for (int r = 0; r < 8; ++r) {
        int row = row0 + rbase + r;
        if (row < n) {
            float sc = dinv[row];
            __half2 ha = __float22half2_rn(make_float2(sc * acc[r].x, sc * acc[r].y));
            __half2 hb = __float22half2_rn(make_float2(sc * acc[r].z, sc * acc[r].w));
            uint2 st;
            st.x = *reinterpret_cast<unsigned int*>(&ha);
            st.y = *reinterpret_cast<unsigned int*>(&hb);
            Y[(size_t)row * D4 + t] = st;
        }
    }
}

// out[i,:] = prelu( dinv[i]*( sum_e XWS[src_e,:] + XWS[i,:] ) + b ), XWS fp16 pre-scaled.
// block (24,16): 24 lanes/node x uint2 (4 fp16); edge loop unrolled x8; fp32 out.
__global__ __launch_bounds__(384) void aggregate_kernel(const uint2* __restrict__ XH,
                                                        const int* __restrict__ csr,
                                                        const int2* __restrict__ rowspan,
                                                        const float* __restrict__ dinv,
                                                        const float4* __restrict__ b4,
                                                        const float4* __restrict__ pa4,
                                                        float4* __restrict__ out4, int n) {
    const int i = blockIdx.x * 16 + threadIdx.y;
    const int t = threadIdx.x;  // 0..23
    if (i >= n) return;
    const int2 be = rowspan[i];
    float4 a = make_float4(0.f, 0.f, 0.f, 0.f);
    int p = be.x;
    const int end = be.y;
    for (; p + 8 <= end; p += 8) {
        int s0 = csr[p + 0];
        int s1 = csr[p + 1];
        int s2 = csr[p + 2];
        int s3 = csr[p + 3];
        int s4 = csr[p + 4];
        int s5 = csr[p + 5];
        int s6 = csr[p + 6];
        int s7 = csr[p + 7];
        uint2 r0 = XH[(size_t)s0 * D4 + t];
        uint2 r1 = XH[(size_t)s1 * D4 + t];
        uint2 r2 = XH[(size_t)s2 * D4 + t];
        uint2 r3 = XH[(size_t)s3 * D4 + t];
        uint2 r4 = XH[(size_t)s4 * D4 + t];
        uint2 r5 = XH[(size_t)s5 * D4 + t];
        uint2 r6 = XH[(size_t)s6 * D4 + t];
        uint2 r7 = XH[(size_t)s7 * D4 + t];
        u2add(r0, a); u2add(r1, a); u2add(r2, a); u2add(r3, a);
        u2add(r4, a); u2add(r5, a); u2add(r6, a); u2add(r7, a);
    }
    if (p + 4 <= end) {
        int s0 = csr[p + 0];
        int s1 = csr[p + 1];
        int s2 = csr[p + 2];
        int s3 = csr[p + 3];
        uint2 r0 = XH[(size_t)s0 * D4 + t];
        uint2 r1 = XH[(size_t)s1 * D4 + t];
        uint2 r2 = XH[(size_t)s2 * D4 + t];
        uint2 r3 = XH[(size_t)s3 * D4 + t];
        u2add(r0, a); u2add(r1, a); u2add(r2, a); u2add(r3, a);
        p += 4;
    }
    for (; p < end; ++p)
        u2add(XH[(size_t)csr[p] * D4 + t], a);
    // self term (pre-scaled row)
    u2add(XH[(size_t)i * D4 + t], a);
    const float di = dinv[i];
    float4 b = b4[t], q = pa4[t];
    float4 v;
    v.x = fmaf(di, a.x, b.x);
    v.y = fmaf(di, a.y, b.y);
    v.z = fmaf(di, a.z, b.z);
    v.w = fmaf(di, a.w, b.w);
    v.x = v.x > 0.f ? v.x : q.x * v.x;
    v.y = v.y > 0.f ? v.y : q.y * v.y;
    v.z = v.z > 0.f ? v.z : q.z * v.z;
    v.w = v.w > 0.f ? v.w : q.w * v.w;
    out4[(size_t)i * D4 + t] = v;
}

extern "C" void kernel_launch(void* const* d_in, const int* in_sizes, int n_in,
                              void* d_out, int out_size, void* d_ws, size_t ws_size,
                              hipStream_t stream) {
    const float* x   = (const float*)d_in[0];
    const int*   ei  = (const int*)d_in[1];
    const float* W1  = (const float*)d_in[2];
    const float* b1  = (const float*)d_in[3];
    const float* W2  = (const float*)d_in[4];
    const float* b2  = (const float*)d_in[5];
    const float* pa  = (const float*)d_in[6];
    const int n = in_sizes[0] / D;
    const int E = in_sizes[1] / 2;
    const int* srcp = ei;
    const int* dstp = ei + E;

    const int nbins = (n + 255) / 256;               // 196
    const int nblk  = (E + 4095) / 4096;             // 196

    char* w = (char*)d_ws;
    int*   cursor  = (int*)w;    w += alignup(256 * 4);
    int*   ebuf    = (int*)w;    w += alignup((size_t)nbins * CAP * 4);
    int*   csr     = (int*)w;    w += alignup((size_t)nbins * CAP * 4);
    float* dinv    = (float*)w;  w += alignup((size_t)n * 4);
    int2*  rowspan = (int2*)w;   w += alignup((size_t)n * 8);
    uint2* xw      = (uint2*)w;  w += alignup((size_t)n * D * 2);  // fp16 pre-scaled rows
    float* out     = (float*)d_out;

    init_kernel<<<1, 256, 0, stream>>>(cursor);
    dist_kernel<<<nblk, 1024, 0, stream>>>(srcp, dstp, E, cursor, ebuf);
    bucketAB_kernel<<<nbins, 256, 0, stream>>>(ebuf, cursor, dinv, rowspan, csr, n);

    dim3 mblk(24, 8);
    const int mgrid = (n + 63) / 64;
    dim3 ablk(24, 16);
    const int agrid = (n + 15) / 16;

    matmul_kernel<<<mgrid, mblk, 0, stream>>>(x, W1, dinv, xw, n);
    aggregate_kernel<<<agrid, ablk, 0, stream>>>(xw, csr, rowspan, dinv,
                                                 (const float4*)b1, (const float4*)pa, (float4*)out, n);
    matmul_kernel<<<mgrid, mblk, 0, stream>>>(out, W2, dinv, xw, n);
    aggregate_kernel<<<agrid, ablk, 0, stream>>>(xw, csr, rowspan, dinv,
                                                 (const float4*)b2, (const float4*)pa, (float4*)out, n);
}